// Round 1
// baseline (1351.310 us; speedup 1.0000x reference)
//
#include <hip/hip_runtime.h>
#include <math.h>

#define F_IN 256
#define HC   256   // H*C
#define H_   4
#define C_   64
#define KTOP 10
#define NEG_SLOPE 0.2f

// ================= GEMM: C[M,No] = A[M,K] @ B[No,K]^T (fp32) =================
#define BM 64
#define BN 64
#define BK 16
__global__ __launch_bounds__(256) void gemm_nt(const float* __restrict__ A,
                                               const float* __restrict__ B,
                                               float* __restrict__ Cc,
                                               int M, int K, int No) {
  __shared__ float As[BK][BM];
  __shared__ float Bs[BK][BN];
  const int bm = blockIdx.x * BM;
  const int bn = blockIdx.y * BN;
  const int tid = threadIdx.x;
  const int tx = tid & 15, ty = tid >> 4;
  const int lr = tid >> 2;          // 0..63
  const int lk = (tid & 3) << 2;    // 0,4,8,12
  float acc[4][4] = {};
  for (int k0 = 0; k0 < K; k0 += BK) {
    float4 av = make_float4(0.f, 0.f, 0.f, 0.f);
    if (bm + lr < M) av = *(const float4*)(A + (size_t)(bm + lr) * K + k0 + lk);
    float4 bv = *(const float4*)(B + (size_t)(bn + lr) * K + k0 + lk);
    __syncthreads();
    As[lk + 0][lr] = av.x; As[lk + 1][lr] = av.y; As[lk + 2][lr] = av.z; As[lk + 3][lr] = av.w;
    Bs[lk + 0][lr] = bv.x; Bs[lk + 1][lr] = bv.y; Bs[lk + 2][lr] = bv.z; Bs[lk + 3][lr] = bv.w;
    __syncthreads();
#pragma unroll
    for (int kk = 0; kk < BK; ++kk) {
      float4 a4 = *(const float4*)&As[kk][ty << 2];
      float4 b4 = *(const float4*)&Bs[kk][tx << 2];
      float a[4] = {a4.x, a4.y, a4.z, a4.w};
      float b[4] = {b4.x, b4.y, b4.z, b4.w};
#pragma unroll
      for (int i = 0; i < 4; ++i)
#pragma unroll
        for (int j = 0; j < 4; ++j) acc[i][j] += a[i] * b[j];
    }
  }
#pragma unroll
  for (int i = 0; i < 4; ++i) {
    int r = bm + (ty << 2) + i;
    if (r < M)
      *(float4*)(Cc + (size_t)r * No + bn + (tx << 2)) =
          make_float4(acc[i][0], acc[i][1], acc[i][2], acc[i][3]);
  }
}

// ============ attention scores: a_s[n,h] = <xl[n,h,:], att_s[h,:]> ============
__global__ __launch_bounds__(256) void att_scores(const float* __restrict__ xl,
                                                  const float* __restrict__ att_s,
                                                  const float* __restrict__ att_d,
                                                  float* __restrict__ as_,
                                                  float* __restrict__ ad_, int n_nodes) {
  int n = blockIdx.x;               // one block per node, wave per head
  int h = threadIdx.x >> 6;
  int lane = threadIdx.x & 63;
  if (n >= n_nodes) return;
  float p = xl[(size_t)n * HC + h * C_ + lane];
  float s = p * att_s[h * C_ + lane];
  float d = p * att_d[h * C_ + lane];
#pragma unroll
  for (int off = 32; off >= 1; off >>= 1) {
    s += __shfl_down(s, off);
    d += __shfl_down(d, off);
  }
  if (lane == 0) {
    as_[n * H_ + h] = s;
    ad_[n * H_ + h] = d;
  }
}

// ====================== CSR build ======================
__global__ void count_edges(const int* __restrict__ dst, int E_, int* __restrict__ counts) {
  int e = blockIdx.x * blockDim.x + threadIdx.x;
  if (e < E_) atomicAdd(&counts[dst[e]], 1);
}

#define SCAN_T 1024
__global__ __launch_bounds__(SCAN_T) void scan_offsets(const int* __restrict__ counts,
                                                       int n_nodes, int* __restrict__ row_start,
                                                       int* __restrict__ wptr, int E_) {
  __shared__ int part[SCAN_T];
  int t = threadIdx.x;
  int chunk = (n_nodes + SCAN_T - 1) / SCAN_T;
  int lo = t * chunk;
  int hi = lo + chunk; if (hi > n_nodes) hi = n_nodes;
  int s = 0;
  for (int i = lo; i < hi; ++i) s += counts[i];
  part[t] = s;
  __syncthreads();
  for (int off = 1; off < SCAN_T; off <<= 1) {
    int v = (t >= off) ? part[t - off] : 0;
    __syncthreads();
    part[t] += v;
    __syncthreads();
  }
  int run = part[t] - s;   // exclusive prefix at chunk start
  for (int i = lo; i < hi; ++i) {
    row_start[i] = run;
    wptr[i] = run;
    run += counts[i];
  }
  if (t == SCAN_T - 1) row_start[n_nodes] = E_;
}

__global__ void scatter_edges(const int* __restrict__ src, const int* __restrict__ dst, int E_,
                              int* __restrict__ wptr, int* __restrict__ csr_src) {
  int e = blockIdx.x * blockDim.x + threadIdx.x;
  if (e < E_) {
    int p = atomicAdd(&wptr[dst[e]], 1);
    csr_src[p] = src[e];
  }
}

// ====================== GAT aggregate (top-K softmax + gather) ======================
// one block per dst node; wave w = head w. CONCAT=1 -> out[N,256]; else mean -> out[N,64]
template <int CONCAT>
__global__ __launch_bounds__(256) void gat_aggregate(const float* __restrict__ xl,
                                                     const float* __restrict__ as_,
                                                     const float* __restrict__ ad_,
                                                     const int* __restrict__ row_start,
                                                     const int* __restrict__ csr_src,
                                                     const float* __restrict__ bias,
                                                     float* __restrict__ out, int n_nodes) {
  __shared__ int   s_src[H_][16];
  __shared__ float s_w[H_][16];
  __shared__ float s_out[H_][C_];
  int n = blockIdx.x;
  int h = threadIdx.x >> 6;
  int lane = threadIdx.x & 63;
  int rs = row_start[n];
  int deg = row_start[n + 1] - rs;
  if (deg > 256) deg = 256;   // safety clamp; max expected deg ~50
  float adv = ad_[n * H_ + h];

  float av[4]; int sv[4];
#pragma unroll
  for (int q = 0; q < 4; ++q) {
    int idx = lane + (q << 6);
    if (idx < deg) {
      int s = csr_src[rs + idx];
      float a = as_[s * H_ + h] + adv;
      av[q] = (a >= 0.f) ? a : NEG_SLOPE * a;
      sv[q] = s;
    } else {
      av[q] = -INFINITY; sv[q] = -1;
    }
  }
  int kcount = deg < KTOP ? deg : KTOP;

  // extract top-kcount in descending order (tie -> lower lane / lower q; ties only
  // come from duplicate edges with identical src, so choice is numerically irrelevant)
  for (int it = 0; it < kcount; ++it) {
    float best = av[0]; int bq = 0;
#pragma unroll
    for (int q = 1; q < 4; ++q)
      if (av[q] > best) { best = av[q]; bq = q; }
    float bv = best; int bl = lane;
#pragma unroll
    for (int off = 32; off >= 1; off >>= 1) {
      float ov = __shfl_down(bv, off);
      int   ol = __shfl_down(bl, off);
      if (ov > bv || (ov == bv && ol < bl)) { bv = ov; bl = ol; }
    }
    bl = __shfl(bl, 0);
    if (lane == bl) {
      s_src[h][it] = sv[bq];
      s_w[h][it] = best;
      av[bq] = -INFINITY;
    }
  }
  __syncthreads();   // uniform: deg/kcount identical across the block's 4 waves

  // softmax over kept edges
  float m = (kcount > 0) ? s_w[h][0] : 0.f;   // first extracted = max
  float ex = (lane < kcount) ? expf(s_w[h][lane] - m) : 0.f;
  float denom = ex;
#pragma unroll
  for (int off = 32; off >= 1; off >>= 1) denom += __shfl_down(denom, off);
  denom = __shfl(denom, 0);
  float inv = (kcount > 0) ? 1.f / denom : 0.f;
  if (lane < kcount) s_w[h][lane] = ex * inv;
  __syncthreads();

  // aggregate: lane = channel
  float acc = 0.f;
  for (int i = 0; i < kcount; ++i) {
    int s = s_src[h][i];
    float w = s_w[h][i];
    acc += w * xl[(size_t)s * HC + h * C_ + lane];
  }
  if (CONCAT) {
    out[(size_t)n * HC + h * C_ + lane] = acc + bias[h * C_ + lane];
  } else {
    s_out[h][lane] = acc;
    __syncthreads();
    if (h == 0) {
      float v = 0.25f * (s_out[0][lane] + s_out[1][lane] + s_out[2][lane] + s_out[3][lane]) +
                bias[lane];
      out[(size_t)n * C_ + lane] = v;
    }
  }
}

// ====================== fused MLP head: relu(h2@Wl1^T+bl1)@Wl2^T+bl2 ======================
#define MLP_NODES 16
__global__ __launch_bounds__(128) void head_mlp(const float* __restrict__ h2,
                                                const float* __restrict__ Wl1,
                                                const float* __restrict__ bl1,
                                                const float* __restrict__ Wl2,
                                                const float* __restrict__ bl2,
                                                float* __restrict__ out, int n_nodes) {
  __shared__ float w1t[64][128];   // w1t[c][t] = Wl1[t][c]
  __shared__ float w2t[128][17];   // w2t[k][o] = Wl2[o][k] (+pad)
  __shared__ float xrow[64];
  __shared__ float hid[128];
  __shared__ float part2[128];
  int t = threadIdx.x;
  for (int i = t; i < 128 * 64; i += 128) { int r = i >> 6, c = i & 63; w1t[c][r] = Wl1[i]; }
  for (int i = t; i < 16 * 128; i += 128) { int o = i >> 7, k = i & 127; w2t[k][o] = Wl2[i]; }
  __syncthreads();
  int base = blockIdx.x * MLP_NODES;
  for (int nn = 0; nn < MLP_NODES; ++nn) {
    int n = base + nn;
    if (n >= n_nodes) break;   // uniform across block
    if (t < 64) xrow[t] = h2[(size_t)n * C_ + t];
    __syncthreads();
    float a = bl1[t];
#pragma unroll 8
    for (int c = 0; c < 64; ++c) a += xrow[c] * w1t[c][t];
    hid[t] = (a > 0.f) ? a : 0.f;
    __syncthreads();
    {
      int o = t >> 3, seg = t & 7;
      float p = 0.f;
#pragma unroll
      for (int j = 0; j < 16; ++j) { int k = (seg << 4) + j; p += hid[k] * w2t[k][o]; }
      part2[t] = p;
    }
    __syncthreads();
    if (t < 16) {
      float ov = bl2[t];
#pragma unroll
      for (int j = 0; j < 8; ++j) ov += part2[(t << 3) + j];
      out[(size_t)n * 16 + t] = ov;
    }
    __syncthreads();
  }
}

// ============================== launcher ==============================
extern "C" void kernel_launch(void* const* d_in, const int* in_sizes, int n_in,
                              void* d_out, int out_size, void* d_ws, size_t ws_size,
                              hipStream_t stream) {
  const float* x      = (const float*)d_in[0];
  const float* W1     = (const float*)d_in[1];
  const float* att_s1 = (const float*)d_in[2];
  const float* att_d1 = (const float*)d_in[3];
  const float* b1     = (const float*)d_in[4];
  const float* W2     = (const float*)d_in[5];
  const float* att_s2 = (const float*)d_in[6];
  const float* att_d2 = (const float*)d_in[7];
  const float* b2     = (const float*)d_in[8];
  const float* Wl1    = (const float*)d_in[9];
  const float* bl1    = (const float*)d_in[10];
  const float* Wl2    = (const float*)d_in[11];
  const float* bl2    = (const float*)d_in[12];
  const int*   eidx   = (const int*)d_in[13];

  const int N_ = in_sizes[0] / F_IN;     // 50000
  const int E_ = in_sizes[13] / 2;       // 800000
  const int* e_src = eidx;
  const int* e_dst = eidx + E_;

  // workspace layout
  char* base = (char*)d_ws;
  size_t off = 0;
  auto alloc = [&](size_t bytes) -> char* {
    char* p = base + off;
    off = (off + bytes + 255) & ~(size_t)255;
    return p;
  };
  float* xl      = (float*)alloc((size_t)N_ * HC * 4);
  float* hbuf    = (float*)alloc((size_t)N_ * HC * 4);   // h1; later h2 (N*64)
  float* as_     = (float*)alloc((size_t)N_ * H_ * 4);
  float* ad_     = (float*)alloc((size_t)N_ * H_ * 4);
  int* counts    = (int*)alloc((size_t)N_ * 4);
  int* row_start = (int*)alloc((size_t)(N_ + 1) * 4);
  int* wptr      = (int*)alloc((size_t)N_ * 4);
  int* csr_src   = (int*)alloc((size_t)E_ * 4);
  (void)ws_size;

  const int eb = (E_ + 255) / 256;

  // ---- CSR build (graph is shared by both conv layers) ----
  hipMemsetAsync(counts, 0, (size_t)N_ * 4, stream);
  count_edges<<<eb, 256, 0, stream>>>(e_dst, E_, counts);
  scan_offsets<<<1, SCAN_T, 0, stream>>>(counts, N_, row_start, wptr, E_);
  scatter_edges<<<eb, 256, 0, stream>>>(e_src, e_dst, E_, wptr, csr_src);

  dim3 ggrid((N_ + BM - 1) / BM, HC / BN);

  // ---- conv1 ----
  gemm_nt<<<ggrid, 256, 0, stream>>>(x, W1, xl, N_, F_IN, HC);
  att_scores<<<N_, 256, 0, stream>>>(xl, att_s1, att_d1, as_, ad_, N_);
  gat_aggregate<1><<<N_, 256, 0, stream>>>(xl, as_, ad_, row_start, csr_src, b1, hbuf, N_);

  // ---- conv2 ----
  gemm_nt<<<ggrid, 256, 0, stream>>>(hbuf, W2, xl, N_, HC, HC);
  att_scores<<<N_, 256, 0, stream>>>(xl, att_s2, att_d2, as_, ad_, N_);
  gat_aggregate<0><<<N_, 256, 0, stream>>>(xl, as_, ad_, row_start, csr_src, b2, hbuf, N_);

  // ---- MLP head ----
  head_mlp<<<(N_ + MLP_NODES - 1) / MLP_NODES, 128, 0, stream>>>(hbuf, Wl1, bl1, Wl2, bl2,
                                                                 (float*)d_out, N_);
}

// Round 6
// 982.055 us; speedup vs baseline: 1.3760x; 1.3760x over previous
//
#include <hip/hip_runtime.h>
#include <math.h>

#define F_IN 256
#define HC   256   // H*C
#define H_   4
#define C_   64
#define KTOP 10
#define NEG_SLOPE 0.2f

// ================= GEMM: C[M,No] = A[M,K] @ B[No,K]^T (fp32) =================
// 128x128 tile, 8x8 per thread. Bit-identical to the 64x64 R1 kernel: each
// output element is a single fma chain over k ascending (association unchanged).
#define BM 128
#define BN 128
#define BK 16
#define LDP (BM + 4)   // padded LDS leading dim (keeps float4 alignment: 132%4==0)
__global__ __launch_bounds__(256) void gemm_nt(const float* __restrict__ A,
                                               const float* __restrict__ B,
                                               float* __restrict__ Cc,
                                               int M, int K, int No) {
  __shared__ float As[BK][LDP];
  __shared__ float Bs[BK][LDP];
  const int bm = blockIdx.x * BM;
  const int bn = blockIdx.y * BN;
  const int tid = threadIdx.x;
  const int tx = tid & 15, ty = tid >> 4;   // 16x16 compute grid
  const int lrow = tid >> 1;                // 0..127
  const int lk   = (tid & 1) << 3;          // 0 or 8
  float acc[8][8] = {};
  for (int k0 = 0; k0 < K; k0 += BK) {
    float4 a0 = make_float4(0.f, 0.f, 0.f, 0.f), a1 = a0;
    if (bm + lrow < M) {
      const float* ap = A + (size_t)(bm + lrow) * K + k0 + lk;
      a0 = *(const float4*)ap;
      a1 = *(const float4*)(ap + 4);
    }
    const float* bp = B + (size_t)(bn + lrow) * K + k0 + lk;
    float4 b0 = *(const float4*)bp;
    float4 b1 = *(const float4*)(bp + 4);
    __syncthreads();
    As[lk + 0][lrow] = a0.x; As[lk + 1][lrow] = a0.y; As[lk + 2][lrow] = a0.z; As[lk + 3][lrow] = a0.w;
    As[lk + 4][lrow] = a1.x; As[lk + 5][lrow] = a1.y; As[lk + 6][lrow] = a1.z; As[lk + 7][lrow] = a1.w;
    Bs[lk + 0][lrow] = b0.x; Bs[lk + 1][lrow] = b0.y; Bs[lk + 2][lrow] = b0.z; Bs[lk + 3][lrow] = b0.w;
    Bs[lk + 4][lrow] = b1.x; Bs[lk + 5][lrow] = b1.y; Bs[lk + 6][lrow] = b1.z; Bs[lk + 7][lrow] = b1.w;
    __syncthreads();
#pragma unroll
    for (int kk = 0; kk < BK; ++kk) {
      float a[8], b[8];
      *(float4*)&a[0] = *(const float4*)&As[kk][ty * 8];
      *(float4*)&a[4] = *(const float4*)&As[kk][ty * 8 + 4];
      *(float4*)&b[0] = *(const float4*)&Bs[kk][tx * 8];
      *(float4*)&b[4] = *(const float4*)&Bs[kk][tx * 8 + 4];
#pragma unroll
      for (int i = 0; i < 8; ++i)
#pragma unroll
        for (int j = 0; j < 8; ++j) acc[i][j] += a[i] * b[j];
    }
  }
#pragma unroll
  for (int i = 0; i < 8; ++i) {
    int r = bm + ty * 8 + i;
    if (r < M) {
      float* cp = Cc + (size_t)r * No + bn + tx * 8;
      *(float4*)cp = make_float4(acc[i][0], acc[i][1], acc[i][2], acc[i][3]);
      *(float4*)(cp + 4) = make_float4(acc[i][4], acc[i][5], acc[i][6], acc[i][7]);
    }
  }
}

// ============ attention scores: a_s[n,h] = <xl[n,h,:], att_s[h,:]> ============
__global__ __launch_bounds__(256) void att_scores(const float* __restrict__ xl,
                                                  const float* __restrict__ att_s,
                                                  const float* __restrict__ att_d,
                                                  float* __restrict__ as_,
                                                  float* __restrict__ ad_, int n_nodes) {
  int n = blockIdx.x;               // one block per node, wave per head
  int h = threadIdx.x >> 6;
  int lane = threadIdx.x & 63;
  if (n >= n_nodes) return;
  float p = xl[(size_t)n * HC + h * C_ + lane];
  float s = p * att_s[h * C_ + lane];
  float d = p * att_d[h * C_ + lane];
#pragma unroll
  for (int off = 32; off >= 1; off >>= 1) {
    s += __shfl_down(s, off);
    d += __shfl_down(d, off);
  }
  if (lane == 0) {
    as_[n * H_ + h] = s;
    ad_[n * H_ + h] = d;
  }
}

// ====================== CSR build ======================
__global__ void count_edges(const int* __restrict__ dst, int E_, int* __restrict__ counts) {
  int e = blockIdx.x * blockDim.x + threadIdx.x;
  if (e < E_) atomicAdd(&counts[dst[e]], 1);
}

#define SCAN_T 1024
__global__ __launch_bounds__(SCAN_T) void scan_offsets(const int* __restrict__ counts,
                                                       int n_nodes, int* __restrict__ row_start,
                                                       int* __restrict__ wptr, int E_) {
  __shared__ int part[SCAN_T];
  int t = threadIdx.x;
  int chunk = (n_nodes + SCAN_T - 1) / SCAN_T;
  int lo = t * chunk;
  int hi = lo + chunk; if (hi > n_nodes) hi = n_nodes;
  int s = 0;
  for (int i = lo; i < hi; ++i) s += counts[i];
  part[t] = s;
  __syncthreads();
  for (int off = 1; off < SCAN_T; off <<= 1) {
    int v = (t >= off) ? part[t - off] : 0;
    __syncthreads();
    part[t] += v;
    __syncthreads();
  }
  int run = part[t] - s;   // exclusive prefix at chunk start
  for (int i = lo; i < hi; ++i) {
    int c = counts[i];
    row_start[i] = run;
    wptr[i] = run;
    run += c;
  }
  if (t == SCAN_T - 1) row_start[n_nodes] = E_;
}

__global__ void scatter_edges(const int* __restrict__ src, const int* __restrict__ dst, int E_,
                              int* __restrict__ wptr, int* __restrict__ csr_src) {
  int e = blockIdx.x * blockDim.x + threadIdx.x;
  if (e < E_) {
    int p = atomicAdd(&wptr[dst[e]], 1);
    csr_src[p] = src[e];
  }
}

// ====================== GAT aggregate (top-K softmax + gather) ======================
// one block per dst node; wave w = head w. CONCAT=1 -> out[N,256]; else mean -> out[N,64]
// Fast path (deg<=64, always taken for this graph): full 64-lane bitonic sort with
// the comparator (v desc, lane asc) — produces exactly R1's extraction sequence
// (unique total-order sort), so lanes 0..kcount-1 write bit-identical s_w/s_src.
// Tail (softmax + aggregation) is verbatim R1.
template <int CONCAT>
__global__ __launch_bounds__(256) void gat_aggregate(const float* __restrict__ xl,
                                                     const float* __restrict__ as_,
                                                     const float* __restrict__ ad_,
                                                     const int* __restrict__ row_start,
                                                     const int* __restrict__ csr_src,
                                                     const float* __restrict__ bias,
                                                     float* __restrict__ out, int n_nodes) {
  __shared__ int   s_src[H_][16];
  __shared__ float s_w[H_][16];
  __shared__ float s_out[H_][C_];
  int n = blockIdx.x;
  int h = threadIdx.x >> 6;
  int lane = threadIdx.x & 63;
  int rs = row_start[n];
  int deg = row_start[n + 1] - rs;
  if (deg > 256) deg = 256;   // safety clamp (matches R1); max expected deg ~50
  float adv = ad_[n * H_ + h];
  int kcount = deg < KTOP ? deg : KTOP;

  if (deg <= 64) {
    // ---- fast path: one candidate per lane, bitonic sort desc ----
    float v; int sv;
    if (lane < deg) {
      int s = csr_src[rs + lane];
      float a = as_[s * H_ + h] + adv;
      v = (a >= 0.f) ? a : NEG_SLOPE * a;
      sv = s;
    } else {
      v = -INFINITY; sv = -1;
    }
    int l = lane;
#pragma unroll
    for (int k = 2; k <= 64; k <<= 1) {
#pragma unroll
      for (int j = k >> 1; j > 0; j >>= 1) {
        float ov = __shfl_xor(v, j);
        int   ol = __shfl_xor(l, j);
        int partner = lane ^ j;
        bool dirDesc = ((lane & k) == 0);
        bool mineFirst = (v > ov) || (v == ov && l < ol);   // same comparator as R1's argmax
        bool keepMine = (dirDesc == (lane < partner)) ? mineFirst : !mineFirst;
        if (!keepMine) { v = ov; l = ol; }
      }
    }
    int swin = __shfl(sv, l);   // winner's src id (pull from original lane)
    if (lane < kcount) {
      s_src[h][lane] = swin;
      s_w[h][lane] = v;
    }
  } else {
    // ---- fallback: R1's original iterative extraction, verbatim ----
    float av[4]; int svr[4];
#pragma unroll
    for (int q = 0; q < 4; ++q) {
      int idx = lane + (q << 6);
      if (idx < deg) {
        int s = csr_src[rs + idx];
        float a = as_[s * H_ + h] + adv;
        av[q] = (a >= 0.f) ? a : NEG_SLOPE * a;
        svr[q] = s;
      } else {
        av[q] = -INFINITY; svr[q] = -1;
      }
    }
    for (int it = 0; it < kcount; ++it) {
      float best = av[0]; int bq = 0;
#pragma unroll
      for (int q = 1; q < 4; ++q)
        if (av[q] > best) { best = av[q]; bq = q; }
      float bv = best; int bl = lane;
#pragma unroll
      for (int off = 32; off >= 1; off >>= 1) {
        float ov = __shfl_down(bv, off);
        int   ol = __shfl_down(bl, off);
        if (ov > bv || (ov == bv && ol < bl)) { bv = ov; bl = ol; }
      }
      bl = __shfl(bl, 0);
      if (lane == bl) {
        s_src[h][it] = svr[bq];
        s_w[h][it] = best;
        av[bq] = -INFINITY;
      }
    }
  }
  __syncthreads();   // uniform: deg/kcount identical across the block's 4 waves

  // ---- softmax over kept edges (verbatim R1) ----
  float m = (kcount > 0) ? s_w[h][0] : 0.f;   // first entry = max
  float ex = (lane < kcount) ? expf(s_w[h][lane] - m) : 0.f;
  float denom = ex;
#pragma unroll
  for (int off = 32; off >= 1; off >>= 1) denom += __shfl_down(denom, off);
  denom = __shfl(denom, 0);
  float inv = (kcount > 0) ? 1.f / denom : 0.f;
  if (lane < kcount) s_w[h][lane] = ex * inv;
  __syncthreads();

  // ---- aggregate: lane = channel (verbatim R1) ----
  float acc = 0.f;
  for (int i = 0; i < kcount; ++i) {
    int s = s_src[h][i];
    float w = s_w[h][i];
    acc += w * xl[(size_t)s * HC + h * C_ + lane];
  }
  if (CONCAT) {
    out[(size_t)n * HC + h * C_ + lane] = acc + bias[h * C_ + lane];
  } else {
    s_out[h][lane] = acc;
    __syncthreads();
    if (h == 0) {
      float v2 = 0.25f * (s_out[0][lane] + s_out[1][lane] + s_out[2][lane] + s_out[3][lane]) +
                 bias[lane];
      out[(size_t)n * C_ + lane] = v2;
    }
  }
}

// ====================== fused MLP head: relu(h2@Wl1^T+bl1)@Wl2^T+bl2 ======================
#define MLP_NODES 16
__global__ __launch_bounds__(128) void head_mlp(const float* __restrict__ h2,
                                                const float* __restrict__ Wl1,
                                                const float* __restrict__ bl1,
                                                const float* __restrict__ Wl2,
                                                const float* __restrict__ bl2,
                                                float* __restrict__ out, int n_nodes) {
  __shared__ float w1t[64][128];   // w1t[c][t] = Wl1[t][c]
  __shared__ float w2t[128][17];   // w2t[k][o] = Wl2[o][k] (+pad)
  __shared__ float xrow[64];
  __shared__ float hid[128];
  __shared__ float part2[128];
  int t = threadIdx.x;
  for (int i = t; i < 128 * 64; i += 128) { int r = i >> 6, c = i & 63; w1t[c][r] = Wl1[i]; }
  for (int i = t; i < 16 * 128; i += 128) { int o = i >> 7, k = i & 127; w2t[k][o] = Wl2[i]; }
  __syncthreads();
  int base = blockIdx.x * MLP_NODES;
  for (int nn = 0; nn < MLP_NODES; ++nn) {
    int n = base + nn;
    if (n >= n_nodes) break;   // uniform across block
    if (t < 64) xrow[t] = h2[(size_t)n * C_ + t];
    __syncthreads();
    float a = bl1[t];
#pragma unroll 8
    for (int c = 0; c < 64; ++c) a += xrow[c] * w1t[c][t];
    hid[t] = (a > 0.f) ? a : 0.f;
    __syncthreads();
    {
      int o = t >> 3, seg = t & 7;
      float p = 0.f;
#pragma unroll
      for (int j = 0; j < 16; ++j) { int k = (seg << 4) + j; p += hid[k] * w2t[k][o]; }
      part2[t] = p;
    }
    __syncthreads();
    if (t < 16) {
      float ov = bl2[t];
#pragma unroll
      for (int j = 0; j < 8; ++j) ov += part2[(t << 3) + j];
      out[(size_t)n * 16 + t] = ov;
    }
    __syncthreads();
  }
}

// ============================== launcher ==============================
extern "C" void kernel_launch(void* const* d_in, const int* in_sizes, int n_in,
                              void* d_out, int out_size, void* d_ws, size_t ws_size,
                              hipStream_t stream) {
  const float* x      = (const float*)d_in[0];
  const float* W1     = (const float*)d_in[1];
  const float* att_s1 = (const float*)d_in[2];
  const float* att_d1 = (const float*)d_in[3];
  const float* b1     = (const float*)d_in[4];
  const float* W2     = (const float*)d_in[5];
  const float* att_s2 = (const float*)d_in[6];
  const float* att_d2 = (const float*)d_in[7];
  const float* b2     = (const float*)d_in[8];
  const float* Wl1    = (const float*)d_in[9];
  const float* bl1    = (const float*)d_in[10];
  const float* Wl2    = (const float*)d_in[11];
  const float* bl2    = (const float*)d_in[12];
  const int*   eidx   = (const int*)d_in[13];

  const int N_ = in_sizes[0] / F_IN;     // 50000
  const int E_ = in_sizes[13] / 2;       // 800000
  const int* e_src = eidx;
  const int* e_dst = eidx + E_;

  // workspace layout (identical to R1)
  char* base = (char*)d_ws;
  size_t off = 0;
  auto alloc = [&](size_t bytes) -> char* {
    char* p = base + off;
    off = (off + bytes + 255) & ~(size_t)255;
    return p;
  };
  float* xl      = (float*)alloc((size_t)N_ * HC * 4);
  float* hbuf    = (float*)alloc((size_t)N_ * HC * 4);   // h1; later h2 (N*64)
  float* as_     = (float*)alloc((size_t)N_ * H_ * 4);
  float* ad_     = (float*)alloc((size_t)N_ * H_ * 4);
  int* counts    = (int*)alloc((size_t)N_ * 4);
  int* row_start = (int*)alloc((size_t)(N_ + 1) * 4);
  int* wptr      = (int*)alloc((size_t)N_ * 4);
  int* csr_src   = (int*)alloc((size_t)E_ * 4);
  (void)ws_size;

  const int eb = (E_ + 255) / 256;

  // ---- CSR build (graph is shared by both conv layers) ----
  hipMemsetAsync(counts, 0, (size_t)N_ * 4, stream);
  count_edges<<<eb, 256, 0, stream>>>(e_dst, E_, counts);
  scan_offsets<<<1, SCAN_T, 0, stream>>>(counts, N_, row_start, wptr, E_);
  scatter_edges<<<eb, 256, 0, stream>>>(e_src, e_dst, E_, wptr, csr_src);

  dim3 ggrid((N_ + BM - 1) / BM, HC / BN);

  // ---- conv1 ----
  gemm_nt<<<ggrid, 256, 0, stream>>>(x, W1, xl, N_, F_IN, HC);
  att_scores<<<N_, 256, 0, stream>>>(xl, att_s1, att_d1, as_, ad_, N_);
  gat_aggregate<1><<<N_, 256, 0, stream>>>(xl, as_, ad_, row_start, csr_src, b1, hbuf, N_);

  // ---- conv2 ----
  gemm_nt<<<ggrid, 256, 0, stream>>>(hbuf, W2, xl, N_, HC, HC);
  att_scores<<<N_, 256, 0, stream>>>(xl, att_s2, att_d2, as_, ad_, N_);
  gat_aggregate<0><<<N_, 256, 0, stream>>>(xl, as_, ad_, row_start, csr_src, b2, hbuf, N_);

  // ---- MLP head ----
  head_mlp<<<(N_ + MLP_NODES - 1) / MLP_NODES, 128, 0, stream>>>(hbuf, Wl1, bl1, Wl2, bl2,
                                                                 (float*)d_out, N_);
}

// Round 7
// 908.164 us; speedup vs baseline: 1.4880x; 1.0814x over previous
//
#include <hip/hip_runtime.h>
#include <math.h>

#define F_IN 256
#define HC   256   // H*C
#define H_   4
#define C_   64
#define KTOP 10
#define NEG_SLOPE 0.2f

// ================= GEMM: C[M,No] = A[M,K] @ B[No,K]^T (fp32) =================
// 128x128 tile, 8x8 per thread. Bit-identical to the 64x64 R1 kernel: each
// output element is a single fma chain over k ascending (association unchanged).
#define BM 128
#define BN 128
#define BK 16
#define LDP (BM + 4)   // padded LDS leading dim (keeps float4 alignment: 132%4==0)
__global__ __launch_bounds__(256) void gemm_nt(const float* __restrict__ A,
                                               const float* __restrict__ B,
                                               float* __restrict__ Cc,
                                               int M, int K, int No) {
  __shared__ float As[BK][LDP];
  __shared__ float Bs[BK][LDP];
  const int bm = blockIdx.x * BM;
  const int bn = blockIdx.y * BN;
  const int tid = threadIdx.x;
  const int tx = tid & 15, ty = tid >> 4;   // 16x16 compute grid
  const int lrow = tid >> 1;                // 0..127
  const int lk   = (tid & 1) << 3;          // 0 or 8
  float acc[8][8] = {};
  for (int k0 = 0; k0 < K; k0 += BK) {
    float4 a0 = make_float4(0.f, 0.f, 0.f, 0.f), a1 = a0;
    if (bm + lrow < M) {
      const float* ap = A + (size_t)(bm + lrow) * K + k0 + lk;
      a0 = *(const float4*)ap;
      a1 = *(const float4*)(ap + 4);
    }
    const float* bp = B + (size_t)(bn + lrow) * K + k0 + lk;
    float4 b0 = *(const float4*)bp;
    float4 b1 = *(const float4*)(bp + 4);
    __syncthreads();
    As[lk + 0][lrow] = a0.x; As[lk + 1][lrow] = a0.y; As[lk + 2][lrow] = a0.z; As[lk + 3][lrow] = a0.w;
    As[lk + 4][lrow] = a1.x; As[lk + 5][lrow] = a1.y; As[lk + 6][lrow] = a1.z; As[lk + 7][lrow] = a1.w;
    Bs[lk + 0][lrow] = b0.x; Bs[lk + 1][lrow] = b0.y; Bs[lk + 2][lrow] = b0.z; Bs[lk + 3][lrow] = b0.w;
    Bs[lk + 4][lrow] = b1.x; Bs[lk + 5][lrow] = b1.y; Bs[lk + 6][lrow] = b1.z; Bs[lk + 7][lrow] = b1.w;
    __syncthreads();
#pragma unroll
    for (int kk = 0; kk < BK; ++kk) {
      float a[8], b[8];
      *(float4*)&a[0] = *(const float4*)&As[kk][ty * 8];
      *(float4*)&a[4] = *(const float4*)&As[kk][ty * 8 + 4];
      *(float4*)&b[0] = *(const float4*)&Bs[kk][tx * 8];
      *(float4*)&b[4] = *(const float4*)&Bs[kk][tx * 8 + 4];
#pragma unroll
      for (int i = 0; i < 8; ++i)
#pragma unroll
        for (int j = 0; j < 8; ++j) acc[i][j] += a[i] * b[j];
    }
  }
#pragma unroll
  for (int i = 0; i < 8; ++i) {
    int r = bm + ty * 8 + i;
    if (r < M) {
      float* cp = Cc + (size_t)r * No + bn + tx * 8;
      *(float4*)cp = make_float4(acc[i][0], acc[i][1], acc[i][2], acc[i][3]);
      *(float4*)(cp + 4) = make_float4(acc[i][4], acc[i][5], acc[i][6], acc[i][7]);
    }
  }
}

// ============ MLP layer 1: hid = relu(A @ B^T + bias), same tiling ============
// (post-top-K: re-association here only perturbs output continuously ~1e-6)
__global__ __launch_bounds__(256) void gemm_bias_relu(const float* __restrict__ A,
                                                      const float* __restrict__ B,
                                                      const float* __restrict__ bias,
                                                      float* __restrict__ Cc,
                                                      int M, int K, int No) {
  __shared__ float As[BK][LDP];
  __shared__ float Bs[BK][LDP];
  const int bm = blockIdx.x * BM;
  const int bn = blockIdx.y * BN;
  const int tid = threadIdx.x;
  const int tx = tid & 15, ty = tid >> 4;
  const int lrow = tid >> 1;
  const int lk   = (tid & 1) << 3;
  float acc[8][8] = {};
  for (int k0 = 0; k0 < K; k0 += BK) {
    float4 a0 = make_float4(0.f, 0.f, 0.f, 0.f), a1 = a0;
    if (bm + lrow < M) {
      const float* ap = A + (size_t)(bm + lrow) * K + k0 + lk;
      a0 = *(const float4*)ap;
      a1 = *(const float4*)(ap + 4);
    }
    float4 b0 = make_float4(0.f, 0.f, 0.f, 0.f), b1 = b0;
    if (bn + lrow < No) {
      const float* bp = B + (size_t)(bn + lrow) * K + k0 + lk;
      b0 = *(const float4*)bp;
      b1 = *(const float4*)(bp + 4);
    }
    __syncthreads();
    As[lk + 0][lrow] = a0.x; As[lk + 1][lrow] = a0.y; As[lk + 2][lrow] = a0.z; As[lk + 3][lrow] = a0.w;
    As[lk + 4][lrow] = a1.x; As[lk + 5][lrow] = a1.y; As[lk + 6][lrow] = a1.z; As[lk + 7][lrow] = a1.w;
    Bs[lk + 0][lrow] = b0.x; Bs[lk + 1][lrow] = b0.y; Bs[lk + 2][lrow] = b0.z; Bs[lk + 3][lrow] = b0.w;
    Bs[lk + 4][lrow] = b1.x; Bs[lk + 5][lrow] = b1.y; Bs[lk + 6][lrow] = b1.z; Bs[lk + 7][lrow] = b1.w;
    __syncthreads();
#pragma unroll
    for (int kk = 0; kk < BK; ++kk) {
      float a[8], b[8];
      *(float4*)&a[0] = *(const float4*)&As[kk][ty * 8];
      *(float4*)&a[4] = *(const float4*)&As[kk][ty * 8 + 4];
      *(float4*)&b[0] = *(const float4*)&Bs[kk][tx * 8];
      *(float4*)&b[4] = *(const float4*)&Bs[kk][tx * 8 + 4];
#pragma unroll
      for (int i = 0; i < 8; ++i)
#pragma unroll
        for (int j = 0; j < 8; ++j) acc[i][j] += a[i] * b[j];
    }
  }
#pragma unroll
  for (int i = 0; i < 8; ++i) {
    int r = bm + ty * 8 + i;
    if (r < M) {
      float* cp = Cc + (size_t)r * No + bn + tx * 8;
#pragma unroll
      for (int j = 0; j < 8; ++j) {
        int col = bn + tx * 8 + j;
        cp[j] = fmaxf(acc[i][j] + bias[col], 0.f);
      }
    }
  }
}

// ============ MLP layer 2: out[n,o] = <hid[n,:], Wl2[o,:]> + bl2[o] ============
__global__ __launch_bounds__(256) void head_out(const float* __restrict__ hid,
                                                const float* __restrict__ Wl2,
                                                const float* __restrict__ bl2,
                                                float* __restrict__ out, int n_nodes) {
  int t = blockIdx.x * 256 + threadIdx.x;
  int n = t >> 4, o = t & 15;
  if (n >= n_nodes) return;
  const float4* hp = (const float4*)(hid + (size_t)n * 128);
  const float4* wp = (const float4*)(Wl2 + (size_t)o * 128);
  float acc = bl2[o];
#pragma unroll
  for (int k = 0; k < 32; ++k) {
    float4 hv = hp[k], wv = wp[k];
    acc += hv.x * wv.x + hv.y * wv.y + hv.z * wv.z + hv.w * wv.w;
  }
  out[(size_t)n * 16 + o] = acc;
}

// ============ attention scores: a_s[n,h] = <xl[n,h,:], att_s[h,:]> ============
__global__ __launch_bounds__(256) void att_scores(const float* __restrict__ xl,
                                                  const float* __restrict__ att_s,
                                                  const float* __restrict__ att_d,
                                                  float* __restrict__ as_,
                                                  float* __restrict__ ad_, int n_nodes) {
  int n = blockIdx.x;               // one block per node, wave per head
  int h = threadIdx.x >> 6;
  int lane = threadIdx.x & 63;
  if (n >= n_nodes) return;
  float p = xl[(size_t)n * HC + h * C_ + lane];
  float s = p * att_s[h * C_ + lane];
  float d = p * att_d[h * C_ + lane];
#pragma unroll
  for (int off = 32; off >= 1; off >>= 1) {
    s += __shfl_down(s, off);
    d += __shfl_down(d, off);
  }
  if (lane == 0) {
    as_[n * H_ + h] = s;
    ad_[n * H_ + h] = d;
  }
}

// ====================== CSR build ======================
__global__ void count_edges(const int* __restrict__ dst, int E_, int* __restrict__ counts) {
  int e = blockIdx.x * blockDim.x + threadIdx.x;
  if (e < E_) atomicAdd(&counts[dst[e]], 1);
}

#define SCAN_T 1024
__global__ __launch_bounds__(SCAN_T) void scan_offsets(const int* __restrict__ counts,
                                                       int n_nodes, int* __restrict__ row_start,
                                                       int* __restrict__ wptr, int E_) {
  __shared__ int part[SCAN_T];
  int t = threadIdx.x;
  int chunk = (n_nodes + SCAN_T - 1) / SCAN_T;
  int lo = t * chunk;
  int hi = lo + chunk; if (hi > n_nodes) hi = n_nodes;
  int s = 0;
  for (int i = lo; i < hi; ++i) s += counts[i];
  part[t] = s;
  __syncthreads();
  for (int off = 1; off < SCAN_T; off <<= 1) {
    int v = (t >= off) ? part[t - off] : 0;
    __syncthreads();
    part[t] += v;
    __syncthreads();
  }
  int run = part[t] - s;   // exclusive prefix at chunk start
  for (int i = lo; i < hi; ++i) {
    int c = counts[i];
    row_start[i] = run;
    wptr[i] = run;
    run += c;
  }
  if (t == SCAN_T - 1) row_start[n_nodes] = E_;
}

__global__ void scatter_edges(const int* __restrict__ src, const int* __restrict__ dst, int E_,
                              int* __restrict__ wptr, int* __restrict__ csr_src) {
  int e = blockIdx.x * blockDim.x + threadIdx.x;
  if (e < E_) {
    int p = atomicAdd(&wptr[dst[e]], 1);
    csr_src[p] = src[e];
  }
}

// ====================== GAT aggregate (top-K softmax + gather) ======================
// one block per dst node; wave w = head w. CONCAT=1 -> out[N,256]; else mean -> out[N,64]
// Fast path (deg<=64, always taken for this graph): full 64-lane bitonic sort with
// the comparator (v desc, lane asc) — produces exactly R1's extraction sequence
// (unique total-order sort), so lanes 0..kcount-1 write bit-identical s_w/s_src.
// Tail (softmax + aggregation) is verbatim R1.
template <int CONCAT>
__global__ __launch_bounds__(256) void gat_aggregate(const float* __restrict__ xl,
                                                     const float* __restrict__ as_,
                                                     const float* __restrict__ ad_,
                                                     const int* __restrict__ row_start,
                                                     const int* __restrict__ csr_src,
                                                     const float* __restrict__ bias,
                                                     float* __restrict__ out, int n_nodes) {
  __shared__ int   s_src[H_][16];
  __shared__ float s_w[H_][16];
  __shared__ float s_out[H_][C_];
  int n = blockIdx.x;
  int h = threadIdx.x >> 6;
  int lane = threadIdx.x & 63;
  int rs = row_start[n];
  int deg = row_start[n + 1] - rs;
  if (deg > 256) deg = 256;   // safety clamp (matches R1); max expected deg ~50
  float adv = ad_[n * H_ + h];
  int kcount = deg < KTOP ? deg : KTOP;

  if (deg <= 64) {
    // ---- fast path: one candidate per lane, bitonic sort desc ----
    float v; int sv;
    if (lane < deg) {
      int s = csr_src[rs + lane];
      float a = as_[s * H_ + h] + adv;
      v = (a >= 0.f) ? a : NEG_SLOPE * a;
      sv = s;
    } else {
      v = -INFINITY; sv = -1;
    }
    int l = lane;
#pragma unroll
    for (int k = 2; k <= 64; k <<= 1) {
#pragma unroll
      for (int j = k >> 1; j > 0; j >>= 1) {
        float ov = __shfl_xor(v, j);
        int   ol = __shfl_xor(l, j);
        int partner = lane ^ j;
        bool dirDesc = ((lane & k) == 0);
        bool mineFirst = (v > ov) || (v == ov && l < ol);   // same comparator as R1's argmax
        bool keepMine = (dirDesc == (lane < partner)) ? mineFirst : !mineFirst;
        if (!keepMine) { v = ov; l = ol; }
      }
    }
    int swin = __shfl(sv, l);   // winner's src id (pull from original lane)
    if (lane < kcount) {
      s_src[h][lane] = swin;
      s_w[h][lane] = v;
    }
  } else {
    // ---- fallback: R1's original iterative extraction, verbatim ----
    float av[4]; int svr[4];
#pragma unroll
    for (int q = 0; q < 4; ++q) {
      int idx = lane + (q << 6);
      if (idx < deg) {
        int s = csr_src[rs + idx];
        float a = as_[s * H_ + h] + adv;
        av[q] = (a >= 0.f) ? a : NEG_SLOPE * a;
        svr[q] = s;
      } else {
        av[q] = -INFINITY; svr[q] = -1;
      }
    }
    for (int it = 0; it < kcount; ++it) {
      float best = av[0]; int bq = 0;
#pragma unroll
      for (int q = 1; q < 4; ++q)
        if (av[q] > best) { best = av[q]; bq = q; }
      float bv = best; int bl = lane;
#pragma unroll
      for (int off = 32; off >= 1; off >>= 1) {
        float ov = __shfl_down(bv, off);
        int   ol = __shfl_down(bl, off);
        if (ov > bv || (ov == bv && ol < bl)) { bv = ov; bl = ol; }
      }
      bl = __shfl(bl, 0);
      if (lane == bl) {
        s_src[h][it] = svr[bq];
        s_w[h][it] = best;
        av[bq] = -INFINITY;
      }
    }
  }
  __syncthreads();   // uniform: deg/kcount identical across the block's 4 waves

  // ---- softmax over kept edges (verbatim R1) ----
  float m = (kcount > 0) ? s_w[h][0] : 0.f;   // first entry = max
  float ex = (lane < kcount) ? expf(s_w[h][lane] - m) : 0.f;
  float denom = ex;
#pragma unroll
  for (int off = 32; off >= 1; off >>= 1) denom += __shfl_down(denom, off);
  denom = __shfl(denom, 0);
  float inv = (kcount > 0) ? 1.f / denom : 0.f;
  if (lane < kcount) s_w[h][lane] = ex * inv;
  __syncthreads();

  // ---- aggregate: lane = channel (verbatim R1) ----
  float acc = 0.f;
  for (int i = 0; i < kcount; ++i) {
    int s = s_src[h][i];
    float w = s_w[h][i];
    acc += w * xl[(size_t)s * HC + h * C_ + lane];
  }
  if (CONCAT) {
    out[(size_t)n * HC + h * C_ + lane] = acc + bias[h * C_ + lane];
  } else {
    s_out[h][lane] = acc;
    __syncthreads();
    if (h == 0) {
      float v2 = 0.25f * (s_out[0][lane] + s_out[1][lane] + s_out[2][lane] + s_out[3][lane]) +
                 bias[lane];
      out[(size_t)n * C_ + lane] = v2;
    }
  }
}

// ============================== launcher ==============================
extern "C" void kernel_launch(void* const* d_in, const int* in_sizes, int n_in,
                              void* d_out, int out_size, void* d_ws, size_t ws_size,
                              hipStream_t stream) {
  const float* x      = (const float*)d_in[0];
  const float* W1     = (const float*)d_in[1];
  const float* att_s1 = (const float*)d_in[2];
  const float* att_d1 = (const float*)d_in[3];
  const float* b1     = (const float*)d_in[4];
  const float* W2     = (const float*)d_in[5];
  const float* att_s2 = (const float*)d_in[6];
  const float* att_d2 = (const float*)d_in[7];
  const float* b2     = (const float*)d_in[8];
  const float* Wl1    = (const float*)d_in[9];
  const float* bl1    = (const float*)d_in[10];
  const float* Wl2    = (const float*)d_in[11];
  const float* bl2    = (const float*)d_in[12];
  const int*   eidx   = (const int*)d_in[13];

  const int N_ = in_sizes[0] / F_IN;     // 50000
  const int E_ = in_sizes[13] / 2;       // 800000
  const int* e_src = eidx;
  const int* e_dst = eidx + E_;

  // workspace layout (identical to R1/R6)
  char* base = (char*)d_ws;
  size_t off = 0;
  auto alloc = [&](size_t bytes) -> char* {
    char* p = base + off;
    off = (off + bytes + 255) & ~(size_t)255;
    return p;
  };
  float* xl      = (float*)alloc((size_t)N_ * HC * 4);
  float* hbuf    = (float*)alloc((size_t)N_ * HC * 4);   // h1; later h2 (N*64)
  float* as_     = (float*)alloc((size_t)N_ * H_ * 4);
  float* ad_     = (float*)alloc((size_t)N_ * H_ * 4);
  int* counts    = (int*)alloc((size_t)N_ * 4);
  int* row_start = (int*)alloc((size_t)(N_ + 1) * 4);
  int* wptr      = (int*)alloc((size_t)N_ * 4);
  int* csr_src   = (int*)alloc((size_t)E_ * 4);
  (void)ws_size;
  // hid buffer for MLP layer 1 reuses xl's space (xl is dead after gat_aggregate<0>;
  // stream order guarantees the aggregate completes before gemm_bias_relu writes here)
  float* hidbuf  = xl;   // N*128 floats <= N*256 slot

  const int eb = (E_ + 255) / 256;

  // ---- CSR build (graph is shared by both conv layers) ----
  hipMemsetAsync(counts, 0, (size_t)N_ * 4, stream);
  count_edges<<<eb, 256, 0, stream>>>(e_dst, E_, counts);
  scan_offsets<<<1, SCAN_T, 0, stream>>>(counts, N_, row_start, wptr, E_);
  scatter_edges<<<eb, 256, 0, stream>>>(e_src, e_dst, E_, wptr, csr_src);

  dim3 ggrid((N_ + BM - 1) / BM, HC / BN);

  // ---- conv1 ----
  gemm_nt<<<ggrid, 256, 0, stream>>>(x, W1, xl, N_, F_IN, HC);
  att_scores<<<N_, 256, 0, stream>>>(xl, att_s1, att_d1, as_, ad_, N_);
  gat_aggregate<1><<<N_, 256, 0, stream>>>(xl, as_, ad_, row_start, csr_src, b1, hbuf, N_);

  // ---- conv2 ----
  gemm_nt<<<ggrid, 256, 0, stream>>>(hbuf, W2, xl, N_, HC, HC);
  att_scores<<<N_, 256, 0, stream>>>(xl, att_s2, att_d2, as_, ad_, N_);
  gat_aggregate<0><<<N_, 256, 0, stream>>>(xl, as_, ad_, row_start, csr_src, b2, hbuf, N_);

  // ---- MLP head: hid = relu(h2 @ Wl1^T + bl1); out = hid @ Wl2^T + bl2 ----
  dim3 hgrid((N_ + BM - 1) / BM, 1);
  gemm_bias_relu<<<hgrid, 256, 0, stream>>>(hbuf, Wl1, bl1, hidbuf, N_, C_, 128);
  head_out<<<(N_ * 16 + 255) / 256, 256, 0, stream>>>(hidbuf, Wl2, bl2, (float*)d_out, N_);
}